// Round 1
// baseline (640.291 us; speedup 1.0000x reference)
//
#include <hip/hip_runtime.h>
#include <math.h>

// SVPF step: B=8, N=2048, D=4, fp32.  3 SVGD iterations.
// log_weight output channel is exactly -log(2048) (log_post cancels).
//
// ws layout (floats):
//   xA[65536] xB[65536] g[65536] step[65536] ap[65536] bc[16384]
//   hpar[32]  (per batch: h, -1/h, 2/h, unused)
//   state[32 ints] (per batch: sel0, sel01, r_after0, r_after1)
//   hist0[8*4096] hist1[8*4096] hist2[8*256]  (ints)
// total ~1.65 MB.

#define NPART 2048
#define NB8   8
#define KRANK 2097151               // (2048*2048-1)/2, lower-median rank
#define LOGN_F 7.6246189861593985f  // log(2048)
#define A_C 0.9f

__device__ __forceinline__ float dot4(const float4 a, const float4 b) {
  return a.x*b.x + a.y*b.y + a.z*b.z + a.w*b.w;
}

// ---------- init: x0 = A*prev + noise; step = 0; ap = A*prev; bc = -0.5|ap|^2
__global__ __launch_bounds__(256) void k_init(const float* __restrict__ prev,
                                              const float* __restrict__ noise,
                                              float* __restrict__ x0,
                                              float* __restrict__ stepb,
                                              float* __restrict__ apb,
                                              float* __restrict__ bcb) {
  int idx = blockIdx.x * 256 + threadIdx.x;   // 0..16383 (B*N)
  float4 p  = ((const float4*)prev)[idx];
  float4 nz = ((const float4*)noise)[idx];
  float4 ap = make_float4(A_C*p.x, A_C*p.y, A_C*p.z, A_C*p.w);
  float4 x  = make_float4(ap.x+nz.x, ap.y+nz.y, ap.z+nz.z, ap.w+nz.w);
  ((float4*)x0)[idx]    = x;
  ((float4*)stepb)[idx] = make_float4(0.f, 0.f, 0.f, 0.f);
  ((float4*)apb)[idx]   = ap;
  bcb[idx] = -0.5f * dot4(ap, ap);
}

// ---------- histogram passes for exact radix-select of median(sq)
// PHASE 0: bits[31:20] -> 4096 bins;  PHASE 1: bits[19:8] -> 4096 bins
// (filtered on sel0);  PHASE 2: bits[7:0] -> 256 bins (filtered on sel01).
template <int PHASE>
__global__ __launch_bounds__(256) void k_hist(const float* __restrict__ x,
                                              const int* __restrict__ state,
                                              int* __restrict__ hist) {
  const int NBIN = (PHASE == 2) ? 256 : 4096;
  int b   = blockIdx.x >> 6;   // 64 blocks per batch
  int blk = blockIdx.x & 63;
  __shared__ float4 sx[NPART];
  __shared__ float  sx2[NPART];
  __shared__ int    sh[(PHASE == 2) ? 256 : 4096];
  for (int t = threadIdx.x; t < NPART; t += 256) {
    float4 v = ((const float4*)x)[b*NPART + t];
    sx[t] = v;
    sx2[t] = dot4(v, v);
  }
  for (int t = threadIdx.x; t < NBIN; t += 256) sh[t] = 0;
  int sel0 = 0, sel01 = 0;
  if (PHASE == 1) sel0  = state[b*4 + 0];
  if (PHASE == 2) sel01 = state[b*4 + 1];
  __syncthreads();

  int lin = blk*256 + threadIdx.x;   // 0..16383
  int j  = lin & 2047;
  int i0 = lin >> 11;                // 0..7
  float4 xj = sx[j];
  float  x2j = sx2[j];
  for (int i = i0; i < NPART; i += 8) {
    float4 xi = sx[i];
    float sq = sx2[i] + x2j - 2.0f*dot4(xi, xj);
    sq = fmaxf(sq, 0.0f);
    unsigned bits = __float_as_uint(sq);
    if (PHASE == 0) {
      atomicAdd(&sh[bits >> 20], 1);
    } else if (PHASE == 1) {
      if ((int)(bits >> 20) == sel0) atomicAdd(&sh[(bits >> 8) & 4095], 1);
    } else {
      if ((int)(bits >> 8) == sel01) atomicAdd(&sh[bits & 255], 1);
    }
  }
  __syncthreads();
  for (int t = threadIdx.x; t < NBIN; t += 256) {
    int c = sh[t];
    if (c) atomicAdd(&hist[b*NBIN + t], c);
  }
}

// ---------- scan: find bin containing target rank, update state / finalize h
template <int PHASE>
__global__ __launch_bounds__(256) void k_scan(const int* __restrict__ hist,
                                              int* __restrict__ state,
                                              float* __restrict__ hpar) {
  const int NBIN = (PHASE == 2) ? 256 : 4096;
  const int CH = NBIN / 256;   // 16 or 1
  int b = blockIdx.x;
  __shared__ int part[256];
  int s = 0;
  for (int c = 0; c < CH; ++c) s += hist[b*NBIN + threadIdx.x*CH + c];
  part[threadIdx.x] = s;
  __syncthreads();
  if (threadIdx.x == 0) {
    int r = (PHASE == 0) ? KRANK : state[b*4 + 1 + PHASE]; // slot2 / slot3
    int cum = 0, ch = 0;
    for (; ch < 256; ++ch) { if (cum + part[ch] > r) break; cum += part[ch]; }
    int bin = ch * CH;
    for (;; ++bin) { int c = hist[b*NBIN + bin]; if (cum + c > r) break; cum += c; }
    r -= cum;
    if (PHASE == 0) {
      state[b*4 + 0] = bin;  state[b*4 + 2] = r;
    } else if (PHASE == 1) {
      state[b*4 + 1] = (state[b*4 + 0] << 12) | bin;  state[b*4 + 3] = r;
    } else {
      unsigned bits = (((unsigned)state[b*4 + 1]) << 8) | (unsigned)bin;
      float med = sqrtf(__uint_as_float(bits));  // k-th smallest distance
      float h = med * med / LOGN_F;              // matches reference rounding
      hpar[b*4 + 0] = h;
      hpar[b*4 + 1] = -1.0f / h;
      hpar[b*4 + 2] = 2.0f / h;
    }
  }
}

// ---------- posterior gradient g_i = A*mean_prev_i + obs - 2*x_i
// softmax over j of s_j = dot(x_i, ap_j) - 0.5|ap_j|^2 (i-terms cancel).
// 8 threads per particle, stride-8 j partition (bank-conflict-free float4).
__global__ __launch_bounds__(256) void k_grad(const float* __restrict__ x,
                                              const float* __restrict__ apb,
                                              const float* __restrict__ bcb,
                                              const float* __restrict__ obs,
                                              float* __restrict__ g) {
  int b = blockIdx.x >> 6;       // 64 blocks/batch, 32 particles/block
  int iblk = blockIdx.x & 63;
  __shared__ float4 sap[NPART];
  __shared__ float  sbc[NPART];
  for (int t = threadIdx.x; t < NPART; t += 256) {
    sap[t] = ((const float4*)apb)[b*NPART + t];
    sbc[t] = bcb[b*NPART + t];
  }
  __syncthreads();
  int sub = threadIdx.x & 7;
  int ii  = threadIdx.x >> 3;
  int i = iblk*32 + ii;
  float4 xi = ((const float4*)x)[b*NPART + i];

  float m = -INFINITY;
#pragma unroll 4
  for (int c = 0; c < 256; ++c) {
    int j = sub + 8*c;
    float s = dot4(xi, sap[j]) + sbc[j];
    m = fmaxf(m, s);
  }
  m = fmaxf(m, __shfl_xor(m, 1));
  m = fmaxf(m, __shfl_xor(m, 2));
  m = fmaxf(m, __shfl_xor(m, 4));

  float sum = 0.f;
  float4 acc = make_float4(0.f, 0.f, 0.f, 0.f);
#pragma unroll 4
  for (int c = 0; c < 256; ++c) {
    int j = sub + 8*c;
    float4 ap = sap[j];
    float s = dot4(xi, ap) + sbc[j];
    float e = __expf(s - m);
    sum += e;
    acc.x += e*ap.x; acc.y += e*ap.y; acc.z += e*ap.z; acc.w += e*ap.w;
  }
#pragma unroll
  for (int d = 1; d < 8; d <<= 1) {
    sum   += __shfl_xor(sum, d);
    acc.x += __shfl_xor(acc.x, d);
    acc.y += __shfl_xor(acc.y, d);
    acc.z += __shfl_xor(acc.z, d);
    acc.w += __shfl_xor(acc.w, d);
  }
  if (sub == 0) {
    float inv = 1.0f / sum;
    float4 ob = ((const float4*)obs)[b];
    float4 gg;
    gg.x = acc.x*inv + ob.x - 2.0f*xi.x;
    gg.y = acc.y*inv + ob.y - 2.0f*xi.y;
    gg.z = acc.z*inv + ob.z - 2.0f*xi.z;
    gg.w = acc.w*inv + ob.w - 2.0f*xi.w;
    ((float4*)g)[b*NPART + i] = gg;
  }
}

// ---------- stein pass + RMSprop update.  LDS: x (32KB) + g (32KB) = 64KB.
__global__ __launch_bounds__(256) void k_stein(const float* __restrict__ x,
                                               const float* __restrict__ g,
                                               const float* __restrict__ hpar,
                                               float* __restrict__ stepb,
                                               float* __restrict__ xout) {
  int b = blockIdx.x >> 6;
  int iblk = blockIdx.x & 63;
  __shared__ float4 sx[NPART];
  __shared__ float4 sg[NPART];
  for (int t = threadIdx.x; t < NPART; t += 256) {
    sx[t] = ((const float4*)x)[b*NPART + t];
    sg[t] = ((const float4*)g)[b*NPART + t];
  }
  __syncthreads();
  float neginvh = hpar[b*4 + 1];
  float two_h   = hpar[b*4 + 2];
  int sub = threadIdx.x & 7;
  int ii  = threadIdx.x >> 3;
  int i = iblk*32 + ii;
  float4 xi = sx[i];
  float x2i = dot4(xi, xi);

  float S0 = 0.f;
  float4 Sx = make_float4(0.f,0.f,0.f,0.f);
  float4 Sg = make_float4(0.f,0.f,0.f,0.f);
#pragma unroll 4
  for (int c = 0; c < 256; ++c) {
    int j = sub + 8*c;
    float4 xj = sx[j];
    float4 gj = sg[j];
    float sq = fmaxf(x2i + dot4(xj, xj) - 2.0f*dot4(xi, xj), 0.0f);
    float e = __expf(sq * neginvh);
    S0 += e;
    Sx.x += e*xj.x; Sx.y += e*xj.y; Sx.z += e*xj.z; Sx.w += e*xj.w;
    Sg.x += e*gj.x; Sg.y += e*gj.y; Sg.z += e*gj.z; Sg.w += e*gj.w;
  }
#pragma unroll
  for (int d = 1; d < 8; d <<= 1) {
    S0   += __shfl_xor(S0, d);
    Sx.x += __shfl_xor(Sx.x, d); Sx.y += __shfl_xor(Sx.y, d);
    Sx.z += __shfl_xor(Sx.z, d); Sx.w += __shfl_xor(Sx.w, d);
    Sg.x += __shfl_xor(Sg.x, d); Sg.y += __shfl_xor(Sg.y, d);
    Sg.z += __shfl_xor(Sg.z, d); Sg.w += __shfl_xor(Sg.w, d);
  }
  if (sub == 0) {
    const float invN = 1.0f / 2048.0f;
    float4 stein;
    stein.x = (Sg.x + two_h*(xi.x*S0 - Sx.x)) * invN;
    stein.y = (Sg.y + two_h*(xi.y*S0 - Sx.y)) * invN;
    stein.z = (Sg.z + two_h*(xi.z*S0 - Sx.z)) * invN;
    stein.w = (Sg.w + two_h*(xi.w*S0 - Sx.w)) * invN;
    float4 st = ((float4*)stepb)[b*NPART + i];
    st.x = 0.9f*st.x + 0.1f*stein.x*stein.x;
    st.y = 0.9f*st.y + 0.1f*stein.y*stein.y;
    st.z = 0.9f*st.z + 0.1f*stein.z*stein.z;
    st.w = 0.9f*st.w + 0.1f*stein.w*stein.w;
    ((float4*)stepb)[b*NPART + i] = st;
    float4 xn;
    xn.x = xi.x + 0.1f*stein.x / (sqrtf(st.x) + 1e-8f);
    xn.y = xi.y + 0.1f*stein.y / (sqrtf(st.y) + 1e-8f);
    xn.z = xi.z + 0.1f*stein.z / (sqrtf(st.z) + 1e-8f);
    xn.w = xi.w + 0.1f*stein.w / (sqrtf(st.w) + 1e-8f);
    ((float4*)xout)[b*NPART + i] = xn;
  }
}

// ---------- output: (B, N, 5) = [x, -logN]
__global__ __launch_bounds__(256) void k_out(const float* __restrict__ x,
                                             float* __restrict__ out) {
  int idx = blockIdx.x * 256 + threadIdx.x;   // 0..16383
  float4 v = ((const float4*)x)[idx];
  float* o = out + (size_t)idx * 5;
  o[0] = v.x; o[1] = v.y; o[2] = v.z; o[3] = v.w;
  o[4] = -LOGN_F;
}

extern "C" void kernel_launch(void* const* d_in, const int* in_sizes, int n_in,
                              void* d_out, int out_size, void* d_ws, size_t ws_size,
                              hipStream_t stream) {
  const float* prev  = (const float*)d_in[0];   // (8,2048,4)
  const float* obs   = (const float*)d_in[1];   // (8,4)
  const float* noise = (const float*)d_in[2];   // (8,2048,4)
  float* out = (float*)d_out;                   // (8,2048,5)

  float* ws = (float*)d_ws;
  float* xA    = ws;
  float* xB    = xA + 65536;
  float* gbuf  = xB + 65536;
  float* stepb = gbuf + 65536;
  float* apb   = stepb + 65536;
  float* bcb   = apb + 65536;
  float* hpar  = bcb + 16384;               // 32 floats
  int*   state = (int*)(hpar + 32);         // 32 ints
  int*   hist0 = state + 32;                // 8*4096
  int*   hist1 = hist0 + 8*4096;            // 8*4096
  int*   hist2 = hist1 + 8*4096;            // 8*256

  k_init<<<64, 256, 0, stream>>>(prev, noise, xA, stepb, apb, bcb);

  float* xc = xA;
  float* xn = xB;
  for (int it = 0; it < 3; ++it) {
    hipMemsetAsync(hist0, 0, (size_t)(8*4096 + 8*4096 + 8*256) * sizeof(int), stream);
    k_hist<0><<<512, 256, 0, stream>>>(xc, state, hist0);
    k_scan<0><<<8, 256, 0, stream>>>(hist0, state, hpar);
    k_hist<1><<<512, 256, 0, stream>>>(xc, state, hist1);
    k_scan<1><<<8, 256, 0, stream>>>(hist1, state, hpar);
    k_hist<2><<<512, 256, 0, stream>>>(xc, state, hist2);
    k_scan<2><<<8, 256, 0, stream>>>(hist2, state, hpar);
    k_grad<<<512, 256, 0, stream>>>(xc, apb, bcb, obs, gbuf);
    k_stein<<<512, 256, 0, stream>>>(xc, gbuf, hpar, stepb, xn);
    float* t = xc; xc = xn; xn = t;
  }
  k_out<<<64, 256, 0, stream>>>(xc, out);
}

// Round 2
// 340.802 us; speedup vs baseline: 1.8788x; 1.8788x over previous
//
#include <hip/hip_runtime.h>
#include <math.h>

// SVPF step: B=8, N=2048, D=4, fp32.  3 SVGD iterations.
// log_weight output channel is exactly -log(2048) (log_post cancels).
//
// R2 changes vs R1:
//  - histogram median-select uses unordered pairs only (circular pairing,
//    counts x2, +N virtual diagonal zeros at scan)  -> half the pair-evals
//  - median truncated to top 24 bits (2 phases, not 3; low 8 bits = midpoint)
//    relative h error <= 2^-16, far below output tolerance
//  - hist LDS 56KB -> 48KB (diff-form sq, no sx2)  -> 3 blocks/CU
//  - k_grad single pass: logit = -0.5*|xi-ap_j|^2 <= 0, max-shift analytic
//  - no hipMemsetAsync: k_init zeroes hists, k_scan1 re-zeroes for next iter
//
// ws layout (floats):
//   xA[65536] xB[65536] g[65536] step[65536] ap[65536]
//   hpar[32]  (per batch: h, -1/h, 2/h, pad)
//   state[32 ints] (per batch: sel0, pad, r_remaining, pad)
//   hist0[8*4096] hist1[8*4096]  (ints)   total ~1.57 MB

#define NPART 2048
#define KRANK 2097151               // (2048*2048-1)/2, lower-median rank
#define LOGN_F 7.6246189861593985f  // log(2048)
#define A_C 0.9f

// ---------- init: x0 = A*prev + noise; step = 0; ap = A*prev; zero hists
__global__ __launch_bounds__(256) void k_init(const float* __restrict__ prev,
                                              const float* __restrict__ noise,
                                              float* __restrict__ x0,
                                              float* __restrict__ stepb,
                                              float* __restrict__ apb,
                                              int* __restrict__ hists) {
  int idx = blockIdx.x * 256 + threadIdx.x;   // 0..16383 (B*N)
  float4 p  = ((const float4*)prev)[idx];
  float4 nz = ((const float4*)noise)[idx];
  float4 ap = make_float4(A_C*p.x, A_C*p.y, A_C*p.z, A_C*p.w);
  float4 x  = make_float4(ap.x+nz.x, ap.y+nz.y, ap.z+nz.z, ap.w+nz.w);
  ((float4*)x0)[idx]    = x;
  ((float4*)stepb)[idx] = make_float4(0.f, 0.f, 0.f, 0.f);
  ((float4*)apb)[idx]   = ap;
  // zero hist0+hist1: 2*8*4096 = 65536 ints over 16384 threads -> 4 each
  ((int4*)hists)[idx] = make_int4(0, 0, 0, 0);
}

// ---------- histogram passes (exact radix-select, top 24 bits)
// Unordered pairs only: (i, (i+k) mod N), k = 1..1024; k==1024 restricted to
// i<1024. Each evaluated pair counts 2 (covers (i,j) and (j,i)).
// PHASE 0: bits[31:20] -> 4096 bins;  PHASE 1: bits[19:8], filtered on sel0.
template <int PHASE>
__global__ __launch_bounds__(256) void k_hist(const float* __restrict__ x,
                                              const int* __restrict__ state,
                                              int* __restrict__ hist) {
  int b    = blockIdx.x >> 6;   // 64 blocks per batch
  int tile = blockIdx.x & 63;
  int itile = tile & 7;         // 8 i-tiles of 256
  int ktile = tile >> 3;        // 8 k-tiles of 128
  __shared__ float4 sx[NPART];  // 32 KB
  __shared__ int    sh[4096];   // 16 KB  -> 48 KB total, 3 blocks/CU
  for (int t = threadIdx.x; t < NPART; t += 256)
    sx[t] = ((const float4*)x)[b*NPART + t];
  for (int t = threadIdx.x; t < 4096; t += 256) sh[t] = 0;
  int sel0 = (PHASE == 1) ? state[b*4 + 0] : 0;
  __syncthreads();

  int i = itile*256 + threadIdx.x;
  float4 xi = sx[i];
  int k0 = ktile*128 + 1;       // k in [k0, k0+127]
#pragma unroll 4
  for (int kk = 0; kk < 128; ++kk) {
    int k = k0 + kk;
    int j = (i + k) & (NPART - 1);
    float4 xj = sx[j];
    float dx = xi.x - xj.x, dy = xi.y - xj.y;
    float dz = xi.z - xj.z, dw = xi.w - xj.w;
    float sq = dx*dx + dy*dy + dz*dz + dw*dw;   // >= 0 by construction
    unsigned bits = __float_as_uint(sq);
    bool ok = (k != 1024) || (i < 1024);
    if (PHASE == 0) {
      if (ok) atomicAdd(&sh[bits >> 20], 2);
    } else {
      if (ok && (int)(bits >> 20) == sel0) atomicAdd(&sh[(bits >> 8) & 4095], 2);
    }
  }
  __syncthreads();
  for (int t = threadIdx.x; t < 4096; t += 256) {
    int c = sh[t];
    if (c) atomicAdd(&hist[b*4096 + t], c);
  }
}

// ---------- scan phase 0: find high-12-bit bin containing rank KRANK
__global__ __launch_bounds__(256) void k_scan0(const int* __restrict__ hist0,
                                               int* __restrict__ state) {
  int b = blockIdx.x;
  __shared__ int part[256];
  int s = 0;
  for (int c = 0; c < 16; ++c) s += hist0[b*4096 + threadIdx.x*16 + c];
  if (threadIdx.x == 0) s += NPART;   // diagonal zeros -> bin 0
  part[threadIdx.x] = s;
  __syncthreads();
  if (threadIdx.x == 0) {
    int r = KRANK, cum = 0, ch = 0;
    for (; ch < 256; ++ch) { if (cum + part[ch] > r) break; cum += part[ch]; }
    int bin = ch * 16;
    for (;; ++bin) {
      int c = hist0[b*4096 + bin] + ((bin == 0) ? NPART : 0);
      if (cum + c > r) break;
      cum += c;
    }
    state[b*4 + 0] = bin;
    state[b*4 + 2] = r - cum;
  }
}

// ---------- scan phase 1: finalize h; zero both hists for the next iteration
__global__ __launch_bounds__(256) void k_scan1(int* __restrict__ hist0,
                                               int* __restrict__ hist1,
                                               const int* __restrict__ state,
                                               float* __restrict__ hpar) {
  int b = blockIdx.x;
  __shared__ int part[256];
  int sel0 = state[b*4 + 0];
  int s = 0;
  for (int c = 0; c < 16; ++c) s += hist1[b*4096 + threadIdx.x*16 + c];
  if (threadIdx.x == 0 && sel0 == 0) s += NPART;  // zeros land in bin 0 iff sel0==0
  part[threadIdx.x] = s;
  __syncthreads();
  if (threadIdx.x == 0) {
    int r = state[b*4 + 2], cum = 0, ch = 0;
    for (; ch < 256; ++ch) { if (cum + part[ch] > r) break; cum += part[ch]; }
    int bin = ch * 16;
    for (;; ++bin) {
      int c = hist1[b*4096 + bin] + ((sel0 == 0 && bin == 0) ? NPART : 0);
      if (cum + c > r) break;
      cum += c;
    }
    // top 24 bits exact; low 8 bits -> midpoint (rel err <= 2^-16)
    unsigned bits = (((unsigned)sel0) << 20) | (((unsigned)bin) << 8) | 128u;
    float med = sqrtf(__uint_as_float(bits));
    float h = med * med / LOGN_F;
    hpar[b*4 + 0] = h;
    hpar[b*4 + 1] = -1.0f / h;
    hpar[b*4 + 2] = 2.0f / h;
  }
  __syncthreads();
  for (int t = threadIdx.x; t < 4096; t += 256) {
    hist0[b*4096 + t] = 0;
    hist1[b*4096 + t] = 0;
  }
}

// ---------- posterior gradient, single pass.
// softmax logit over j: log N(x_i; ap_j, I) ~ -0.5|x_i - ap_j|^2  (<= 0, so
// no max pass needed; exact softmax shift-invariance; sum cannot underflow
// because some ap_j lies within ~|noise| of x_i).
// g_i = sum_j w_ij * ap_j + obs - 2 x_i
__global__ __launch_bounds__(256) void k_grad(const float* __restrict__ x,
                                              const float* __restrict__ apb,
                                              const float* __restrict__ obs,
                                              float* __restrict__ g) {
  int b = blockIdx.x >> 6;       // 64 blocks/batch, 32 particles/block
  int iblk = blockIdx.x & 63;
  __shared__ float4 sap[NPART];  // 32 KB -> 5 blocks/CU
  for (int t = threadIdx.x; t < NPART; t += 256)
    sap[t] = ((const float4*)apb)[b*NPART + t];
  __syncthreads();
  int sub = threadIdx.x & 7;
  int ii  = threadIdx.x >> 3;
  int i = iblk*32 + ii;
  float4 xi = ((const float4*)x)[b*NPART + i];

  float sum = 0.f;
  float4 acc = make_float4(0.f, 0.f, 0.f, 0.f);
#pragma unroll 4
  for (int c = 0; c < 256; ++c) {
    int j = sub + 8*c;
    float4 ap = sap[j];
    float dx = xi.x - ap.x, dy = xi.y - ap.y;
    float dz = xi.z - ap.z, dw = xi.w - ap.w;
    float e = __expf(-0.5f*(dx*dx + dy*dy + dz*dz + dw*dw));
    sum += e;
    acc.x += e*ap.x; acc.y += e*ap.y; acc.z += e*ap.z; acc.w += e*ap.w;
  }
#pragma unroll
  for (int d = 1; d < 8; d <<= 1) {
    sum   += __shfl_xor(sum, d);
    acc.x += __shfl_xor(acc.x, d);
    acc.y += __shfl_xor(acc.y, d);
    acc.z += __shfl_xor(acc.z, d);
    acc.w += __shfl_xor(acc.w, d);
  }
  if (sub == 0) {
    float inv = 1.0f / sum;
    float4 ob = ((const float4*)obs)[b];
    float4 gg;
    gg.x = acc.x*inv + ob.x - 2.0f*xi.x;
    gg.y = acc.y*inv + ob.y - 2.0f*xi.y;
    gg.z = acc.z*inv + ob.z - 2.0f*xi.z;
    gg.w = acc.w*inv + ob.w - 2.0f*xi.w;
    ((float4*)g)[b*NPART + i] = gg;
  }
}

// ---------- stein pass + RMSprop update.  LDS: x (32KB) + g (32KB) = 64KB.
__global__ __launch_bounds__(256) void k_stein(const float* __restrict__ x,
                                               const float* __restrict__ g,
                                               const float* __restrict__ hpar,
                                               float* __restrict__ stepb,
                                               float* __restrict__ xout) {
  int b = blockIdx.x >> 6;
  int iblk = blockIdx.x & 63;
  __shared__ float4 sx[NPART];
  __shared__ float4 sg[NPART];
  for (int t = threadIdx.x; t < NPART; t += 256) {
    sx[t] = ((const float4*)x)[b*NPART + t];
    sg[t] = ((const float4*)g)[b*NPART + t];
  }
  __syncthreads();
  float neginvh = hpar[b*4 + 1];
  float two_h   = hpar[b*4 + 2];
  int sub = threadIdx.x & 7;
  int ii  = threadIdx.x >> 3;
  int i = iblk*32 + ii;
  float4 xi = sx[i];

  float S0 = 0.f;
  float4 Sx = make_float4(0.f,0.f,0.f,0.f);
  float4 Sg = make_float4(0.f,0.f,0.f,0.f);
#pragma unroll 4
  for (int c = 0; c < 256; ++c) {
    int j = sub + 8*c;
    float4 xj = sx[j];
    float4 gj = sg[j];
    float dx = xi.x - xj.x, dy = xi.y - xj.y;
    float dz = xi.z - xj.z, dw = xi.w - xj.w;
    float sq = dx*dx + dy*dy + dz*dz + dw*dw;
    float e = __expf(sq * neginvh);
    S0 += e;
    Sx.x += e*xj.x; Sx.y += e*xj.y; Sx.z += e*xj.z; Sx.w += e*xj.w;
    Sg.x += e*gj.x; Sg.y += e*gj.y; Sg.z += e*gj.z; Sg.w += e*gj.w;
  }
#pragma unroll
  for (int d = 1; d < 8; d <<= 1) {
    S0   += __shfl_xor(S0, d);
    Sx.x += __shfl_xor(Sx.x, d); Sx.y += __shfl_xor(Sx.y, d);
    Sx.z += __shfl_xor(Sx.z, d); Sx.w += __shfl_xor(Sx.w, d);
    Sg.x += __shfl_xor(Sg.x, d); Sg.y += __shfl_xor(Sg.y, d);
    Sg.z += __shfl_xor(Sg.z, d); Sg.w += __shfl_xor(Sg.w, d);
  }
  if (sub == 0) {
    const float invN = 1.0f / 2048.0f;
    float4 stein;
    stein.x = (Sg.x + two_h*(xi.x*S0 - Sx.x)) * invN;
    stein.y = (Sg.y + two_h*(xi.y*S0 - Sx.y)) * invN;
    stein.z = (Sg.z + two_h*(xi.z*S0 - Sx.z)) * invN;
    stein.w = (Sg.w + two_h*(xi.w*S0 - Sx.w)) * invN;
    float4 st = ((float4*)stepb)[b*NPART + i];
    st.x = 0.9f*st.x + 0.1f*stein.x*stein.x;
    st.y = 0.9f*st.y + 0.1f*stein.y*stein.y;
    st.z = 0.9f*st.z + 0.1f*stein.z*stein.z;
    st.w = 0.9f*st.w + 0.1f*stein.w*stein.w;
    ((float4*)stepb)[b*NPART + i] = st;
    float4 xn;
    xn.x = xi.x + 0.1f*stein.x / (sqrtf(st.x) + 1e-8f);
    xn.y = xi.y + 0.1f*stein.y / (sqrtf(st.y) + 1e-8f);
    xn.z = xi.z + 0.1f*stein.z / (sqrtf(st.z) + 1e-8f);
    xn.w = xi.w + 0.1f*stein.w / (sqrtf(st.w) + 1e-8f);
    ((float4*)xout)[b*NPART + i] = xn;
  }
}

// ---------- output: (B, N, 5) = [x, -logN]
__global__ __launch_bounds__(256) void k_out(const float* __restrict__ x,
                                             float* __restrict__ out) {
  int idx = blockIdx.x * 256 + threadIdx.x;   // 0..16383
  float4 v = ((const float4*)x)[idx];
  float* o = out + (size_t)idx * 5;
  o[0] = v.x; o[1] = v.y; o[2] = v.z; o[3] = v.w;
  o[4] = -LOGN_F;
}

extern "C" void kernel_launch(void* const* d_in, const int* in_sizes, int n_in,
                              void* d_out, int out_size, void* d_ws, size_t ws_size,
                              hipStream_t stream) {
  const float* prev  = (const float*)d_in[0];   // (8,2048,4)
  const float* obs   = (const float*)d_in[1];   // (8,4)
  const float* noise = (const float*)d_in[2];   // (8,2048,4)
  float* out = (float*)d_out;                   // (8,2048,5)

  float* ws = (float*)d_ws;
  float* xA    = ws;
  float* xB    = xA + 65536;
  float* gbuf  = xB + 65536;
  float* stepb = gbuf + 65536;
  float* apb   = stepb + 65536;
  float* hpar  = apb + 65536;               // 32 floats
  int*   state = (int*)(hpar + 32);         // 32 ints
  int*   hist0 = state + 32;                // 8*4096 ints
  int*   hist1 = hist0 + 8*4096;            // 8*4096 ints

  k_init<<<64, 256, 0, stream>>>(prev, noise, xA, stepb, apb, hist0);

  float* xc = xA;
  float* xn = xB;
  for (int it = 0; it < 3; ++it) {
    k_hist<0><<<512, 256, 0, stream>>>(xc, state, hist0);
    k_scan0<<<8, 256, 0, stream>>>(hist0, state);
    k_hist<1><<<512, 256, 0, stream>>>(xc, state, hist1);
    k_scan1<<<8, 256, 0, stream>>>(hist0, hist1, state, hpar);
    k_grad<<<512, 256, 0, stream>>>(xc, apb, obs, gbuf);
    k_stein<<<512, 256, 0, stream>>>(xc, gbuf, hpar, stepb, xn);
    float* t = xc; xc = xn; xn = t;
  }
  k_out<<<64, 256, 0, stream>>>(xc, out);
}